// Round 2
// baseline (1188.028 us; speedup 1.0000x reference)
//
#include <hip/hip_runtime.h>
#include <hip/hip_bf16.h>

#define Bb 4
#define Ss 2048
#define Dm 1024
#define Hh 16
#define DKk 64
#define DVv 64

using short8  = __attribute__((ext_vector_type(8))) short;
using short4v = __attribute__((ext_vector_type(4))) short;
using floatx4 = __attribute__((ext_vector_type(4))) float;
typedef unsigned short ushort_t;

__device__ inline unsigned short f32_to_bf16(float f) {
    union { float f; unsigned int u; } x; x.f = f;
    unsigned int r = x.u + 0x7fffu + ((x.u >> 16) & 1u);
    return (unsigned short)(r >> 16);
}

// ---------------------------------------------------------------------------
// Weight transpose + cast: W (K=1024, N=1024) fp32 -> Wt (N, K) bf16
// ---------------------------------------------------------------------------
__global__ __launch_bounds__(256) void transpose_w(const float* __restrict__ W,
                                                   unsigned short* __restrict__ Wt) {
    __shared__ float tile[32][33];
    int n0 = blockIdx.x * 32, k0 = blockIdx.y * 32;
    int tx = threadIdx.x, ty = threadIdx.y;   // (32, 8)
    #pragma unroll
    for (int i = 0; i < 32; i += 8)
        tile[ty + i][tx] = W[(size_t)(k0 + ty + i) * Dm + n0 + tx];
    __syncthreads();
    #pragma unroll
    for (int i = 0; i < 32; i += 8)
        Wt[(size_t)(n0 + ty + i) * Dm + k0 + tx] = f32_to_bf16(tile[tx][ty + i]);
}

// ---------------------------------------------------------------------------
// Projection GEMM: A (8192 x 1024 fp32) @ Wt^T (+bias) -> bf16 out
// mode 0: out[((b*H+h)*S + s)*64 + d]   (Q, K layout)
// mode 1: out[((b*H+h)*64 + d)*S + s]   (V transposed layout)
// ---------------------------------------------------------------------------
__global__ __launch_bounds__(256) void gemm_proj(const float* __restrict__ A,
                                                 const unsigned short* __restrict__ Bt,
                                                 const float* __restrict__ bias,
                                                 unsigned short* __restrict__ Out,
                                                 int mode) {
    const int wave = threadIdx.x >> 6;
    const int lane = threadIdx.x & 63;
    const int quad = lane >> 4;
    const int l16  = lane & 15;
    const int row_base = blockIdx.x * 64 + (wave & 1) * 32;
    const int col_base = blockIdx.y * 128 + (wave >> 1) * 64;

    floatx4 acc[2][4] = {};

    for (int k0 = 0; k0 < Dm; k0 += 32) {
        const int kk = k0 + quad * 8;
        short8 a[2], b[4];
        #pragma unroll
        for (int r = 0; r < 2; r++) {
            const floatx4* ap = (const floatx4*)(A + (size_t)(row_base + r * 16 + l16) * Dm + kk);
            floatx4 f0 = ap[0], f1 = ap[1];
            union { short8 v; unsigned short u[8]; } av;
            #pragma unroll
            for (int j = 0; j < 4; j++) {
                av.u[j]     = f32_to_bf16(f0[j]);
                av.u[4 + j] = f32_to_bf16(f1[j]);
            }
            a[r] = av.v;
        }
        #pragma unroll
        for (int c = 0; c < 4; c++)
            b[c] = *(const short8*)(Bt + (size_t)(col_base + c * 16 + l16) * Dm + kk);
        #pragma unroll
        for (int r = 0; r < 2; r++)
            #pragma unroll
            for (int c = 0; c < 4; c++)
                acc[r][c] = __builtin_amdgcn_mfma_f32_16x16x32_bf16(a[r], b[c], acc[r][c], 0, 0, 0);
    }

    #pragma unroll
    for (int r = 0; r < 2; r++)
        #pragma unroll
        for (int c = 0; c < 4; c++) {
            int n = col_base + c * 16 + l16;
            float bias_n = bias[n];
            int h = n >> 6, d = n & 63;
            #pragma unroll
            for (int i = 0; i < 4; i++) {
                int m = row_base + r * 16 + quad * 4 + i;
                unsigned short ob = f32_to_bf16(acc[r][c][i] + bias_n);
                int bb = m >> 11, s = m & (Ss - 1);
                if (mode == 0)
                    Out[((size_t)(bb * Hh + h) * Ss + s) * 64 + d] = ob;
                else
                    Out[((size_t)(bb * Hh + h) * 64 + d) * Ss + s] = ob;
            }
        }
}

// ---------------------------------------------------------------------------
// Flash attention, transposed-scores form.
// One block (4 waves) per (b, h, 64-row q-tile); each wave owns 16 q rows
// and free-runs (NO __syncthreads — P transpose LDS is per-wave private).
// S^T = K . Q^T  (A=K tile, B=Q frag)  => C-layout: col=l16=query,
// row=quad*4+i=key  => softmax reduction = 15 reg ops + 2 shuffles.
// m/l online-softmax state: one scalar per lane (query = l16).
// Qp/Kp: (B*H, S, 64) bf16; Vt: (B*H, 64, S) bf16; AO: (B, S, 1024) bf16
// ---------------------------------------------------------------------------
#define PSTRIDE 72   // ushorts per P row (144 B) -> conflict-free b64/b128
#define SCL 0.18033688f      // 0.125 * log2(e)
#define PEN 1.44269504e12f   // 1e12 * log2(e)  (matches reference NEG_BIG)

__global__ __launch_bounds__(256) void attn_kernel(const unsigned short* __restrict__ Qp,
                                                   const unsigned short* __restrict__ Kp,
                                                   const unsigned short* __restrict__ Vt,
                                                   const int* __restrict__ v_mask,
                                                   unsigned short* __restrict__ AO) {
    const int wave = threadIdx.x >> 6;
    const int lane = threadIdx.x & 63;
    const int quad = lane >> 4;
    const int l16  = lane & 15;
    const int qt = blockIdx.x;
    const int h  = blockIdx.y;
    const int b  = blockIdx.z;
    const int bh = b * Hh + h;
    const int qbase = qt * 64 + wave * 16;
    const int query = qbase + l16;

    __shared__ __align__(16) unsigned short P_lds[4][16 * PSTRIDE];
    unsigned short* Pw = &P_lds[wave][0];

    // Q B-fragments (n = query = l16, k = quad*8+j [+32])
    const unsigned short* qptr = Qp + ((size_t)bh * Ss + qbase + l16) * 64 + quad * 8;
    const short8 qf0 = *(const short8*)(qptr);
    const short8 qf1 = *(const short8*)(qptr + 32);

    floatx4 o[4] = {};
    float mrun = -3e38f;   // per query (=l16), uniform across quads
    float lrun = 0.f;

    for (int kt = 0; kt <= qt; kt++) {
        const int kk = kt * 64;
        const bool diag = (kt == qt);

        // --- S^T = K . Q^T : A = K rows (m = key), B = Q ---
        floatx4 st[4];
        const unsigned short* kbase = Kp + ((size_t)bh * Ss + kk) * 64;
        #pragma unroll
        for (int kf = 0; kf < 4; kf++) {
            const unsigned short* kp = kbase + (size_t)(kf * 16 + l16) * 64 + quad * 8;
            short8 a0 = *(const short8*)(kp);
            short8 a1 = *(const short8*)(kp + 32);
            floatx4 t = {};
            t = __builtin_amdgcn_mfma_f32_16x16x32_bf16(a0, qf0, t, 0, 0, 0);
            t = __builtin_amdgcn_mfma_f32_16x16x32_bf16(a1, qf1, t, 0, 0, 0);
            st[kf] = t;
        }

        // --- scale + mask (log2 domain), per-lane max over 16 keys ---
        float sv[4][4];
        float mloc = -3e38f;
        #pragma unroll
        for (int kf = 0; kf < 4; kf++) {
            const int4 vm = *(const int4*)(v_mask + b * Ss + kk + kf * 16 + quad * 4);
            const int vmi[4] = {vm.x, vm.y, vm.z, vm.w};
            #pragma unroll
            for (int i = 0; i < 4; i++) {
                const int key = kk + kf * 16 + quad * 4 + i;
                float pen = (vmi[i] == 0) ? PEN : 0.f;
                if (diag && key > query) pen += PEN;
                sv[kf][i] = fmaf(st[kf][i], SCL, -pen);
                mloc = fmaxf(mloc, sv[kf][i]);
            }
        }
        // cross-quad butterfly (2 shuffles) -> max over all 64 keys
        mloc = fmaxf(mloc, __shfl_xor(mloc, 16, 64));
        mloc = fmaxf(mloc, __shfl_xor(mloc, 32, 64));
        const float mnew = fmaxf(mrun, mloc);
        const float alpha = exp2f(mrun - mnew);
        mrun = mnew;

        // --- exp, per-lane sum, pack P^T -> LDS as P[query][key_local] ---
        float ps = 0.f;
        #pragma unroll
        for (int kf = 0; kf < 4; kf++) {
            union { short4v v; unsigned short u[4]; } pk;
            #pragma unroll
            for (int i = 0; i < 4; i++) {
                const float p = exp2f(sv[kf][i] - mnew);
                ps += p;
                pk.u[i] = f32_to_bf16(p);
            }
            *(short4v*)(Pw + l16 * PSTRIDE + kf * 16 + quad * 4) = pk.v;
        }
        ps += __shfl_xor(ps, 16, 64);
        ps += __shfl_xor(ps, 32, 64);
        lrun = lrun * alpha + ps;

        // --- rescale O by alpha (redistribute query->row axis: 4 bpermute) ---
        float ai[4];
        #pragma unroll
        for (int i = 0; i < 4; i++)
            ai[i] = __shfl(alpha, quad * 4 + i, 64);
        #pragma unroll
        for (int f = 0; f < 4; f++)
            #pragma unroll
            for (int i = 0; i < 4; i++)
                o[f][i] *= ai[i];

        // --- P A-frags from LDS (per-wave private; in-wave DS order suffices) ---
        const short8 pa0 = *(const short8*)(Pw + l16 * PSTRIDE + quad * 8);
        const short8 pa1 = *(const short8*)(Pw + l16 * PSTRIDE + 32 + quad * 8);

        // --- O += P . V : B = Vt rows (n = dv), k = key ---
        const unsigned short* vb = Vt + (size_t)bh * 64 * Ss + kk;
        #pragma unroll
        for (int f = 0; f < 4; f++) {
            const unsigned short* vp = vb + (size_t)(f * 16 + l16) * Ss + quad * 8;
            short8 v0 = *(const short8*)(vp);
            short8 v1 = *(const short8*)(vp + 32);
            o[f] = __builtin_amdgcn_mfma_f32_16x16x32_bf16(pa0, v0, o[f], 0, 0, 0);
            o[f] = __builtin_amdgcn_mfma_f32_16x16x32_bf16(pa1, v1, o[f], 0, 0, 0);
        }
    }

    // epilogue: divide by row sums (redistribute l), write (B, S, H*64) bf16
    float ri[4];
    #pragma unroll
    for (int i = 0; i < 4; i++)
        ri[i] = 1.0f / __shfl(lrun, quad * 4 + i, 64);
    #pragma unroll
    for (int f = 0; f < 4; f++) {
        const int d = h * 64 + f * 16 + l16;
        #pragma unroll
        for (int i = 0; i < 4; i++) {
            const float val = o[f][i] * ri[i];
            AO[((size_t)b * Ss + qbase + quad * 4 + i) * (Hh * DVv) + d] = f32_to_bf16(val);
        }
    }
}

// ---------------------------------------------------------------------------
// Output GEMM: AO (8192 x 1024 bf16) @ Wot^T + bo, * q_mask -> fp32 d_out
// ---------------------------------------------------------------------------
__global__ __launch_bounds__(256) void gemm_final(const unsigned short* __restrict__ A,
                                                  const unsigned short* __restrict__ Bt,
                                                  const float* __restrict__ bias,
                                                  const int* __restrict__ q_mask,
                                                  float* __restrict__ Out) {
    const int wave = threadIdx.x >> 6;
    const int lane = threadIdx.x & 63;
    const int quad = lane >> 4;
    const int l16  = lane & 15;
    const int row_base = blockIdx.x * 64 + (wave & 1) * 32;
    const int col_base = blockIdx.y * 128 + (wave >> 1) * 64;

    floatx4 acc[2][4] = {};

    for (int k0 = 0; k0 < Dm; k0 += 32) {
        const int kk = k0 + quad * 8;
        short8 a[2], b[4];
        #pragma unroll
        for (int r = 0; r < 2; r++)
            a[r] = *(const short8*)(A + (size_t)(row_base + r * 16 + l16) * Dm + kk);
        #pragma unroll
        for (int c = 0; c < 4; c++)
            b[c] = *(const short8*)(Bt + (size_t)(col_base + c * 16 + l16) * Dm + kk);
        #pragma unroll
        for (int r = 0; r < 2; r++)
            #pragma unroll
            for (int c = 0; c < 4; c++)
                acc[r][c] = __builtin_amdgcn_mfma_f32_16x16x32_bf16(a[r], b[c], acc[r][c], 0, 0, 0);
    }

    #pragma unroll
    for (int r = 0; r < 2; r++)
        #pragma unroll
        for (int c = 0; c < 4; c++) {
            int n = col_base + c * 16 + l16;
            float bias_n = bias[n];
            #pragma unroll
            for (int i = 0; i < 4; i++) {
                int m = row_base + r * 16 + quad * 4 + i;
                float qm = (float)q_mask[m];
                Out[(size_t)m * Dm + n] = (acc[r][c][i] + bias_n) * qm;
            }
        }
}

// ---------------------------------------------------------------------------
extern "C" void kernel_launch(void* const* d_in, const int* in_sizes, int n_in,
                              void* d_out, int out_size, void* d_ws, size_t ws_size,
                              hipStream_t stream) {
    const float* q      = (const float*)d_in[0];
    const float* k      = (const float*)d_in[1];
    const float* v      = (const float*)d_in[2];
    const int*   q_mask = (const int*)d_in[3];
    const int*   v_mask = (const int*)d_in[4];
    const float* Wq     = (const float*)d_in[5];
    const float* bq     = (const float*)d_in[6];
    const float* Wk     = (const float*)d_in[7];
    const float* bk     = (const float*)d_in[8];
    const float* Wv     = (const float*)d_in[9];
    const float* bv     = (const float*)d_in[10];
    const float* Wo     = (const float*)d_in[11];
    const float* bo     = (const float*)d_in[12];
    float* out = (float*)d_out;

    char* ws = (char*)d_ws;
    const size_t WT_SZ = (size_t)Dm * Dm * 2;                 // 2 MB each
    const size_t QP_SZ = (size_t)Bb * Hh * Ss * 64 * 2;       // 16 MB each
    unsigned short* Wtq = (unsigned short*)(ws);
    unsigned short* Wtk = (unsigned short*)(ws + WT_SZ);
    unsigned short* Wtv = (unsigned short*)(ws + 2 * WT_SZ);
    unsigned short* Wto = (unsigned short*)(ws + 3 * WT_SZ);
    unsigned short* Qp  = (unsigned short*)(ws + 4 * WT_SZ);
    unsigned short* Kp  = (unsigned short*)(ws + 4 * WT_SZ + QP_SZ);
    unsigned short* Vt  = (unsigned short*)(ws + 4 * WT_SZ + 2 * QP_SZ);
    unsigned short* AO  = (unsigned short*)(ws + 4 * WT_SZ + 3 * QP_SZ);

    dim3 tb(32, 8);
    dim3 tg(Dm / 32, Dm / 32);
    hipLaunchKernelGGL(transpose_w, tg, tb, 0, stream, Wq, Wtq);
    hipLaunchKernelGGL(transpose_w, tg, tb, 0, stream, Wk, Wtk);
    hipLaunchKernelGGL(transpose_w, tg, tb, 0, stream, Wv, Wtv);
    hipLaunchKernelGGL(transpose_w, tg, tb, 0, stream, Wo, Wto);

    const int M = Bb * Ss;  // 8192
    dim3 pg(M / 64, Dm / 128);
    hipLaunchKernelGGL(gemm_proj, pg, dim3(256), 0, stream, q, Wtq, bq, Qp, 0);
    hipLaunchKernelGGL(gemm_proj, pg, dim3(256), 0, stream, k, Wtk, bk, Kp, 0);
    hipLaunchKernelGGL(gemm_proj, pg, dim3(256), 0, stream, v, Wtv, bv, Vt, 1);

    dim3 ag(Ss / 64, Hh, Bb);
    hipLaunchKernelGGL(attn_kernel, ag, dim3(256), 0, stream, Qp, Kp, Vt, v_mask, AO);

    dim3 fg(M / 64, Dm / 128);
    hipLaunchKernelGGL(gemm_final, fg, dim3(256), 0, stream, AO, Wto, bo, q_mask, out);
}

// Round 3
// 796.067 us; speedup vs baseline: 1.4924x; 1.4924x over previous
//
#include <hip/hip_runtime.h>
#include <hip/hip_bf16.h>

#define Bb 4
#define Ss 2048
#define Dm 1024
#define Hh 16
#define DKk 64
#define DVv 64

using short8  = __attribute__((ext_vector_type(8))) short;
using short4v = __attribute__((ext_vector_type(4))) short;
using floatx4 = __attribute__((ext_vector_type(4))) float;

__device__ inline unsigned short f32_to_bf16(float f) {
    union { float f; unsigned int u; } x; x.f = f;
    unsigned int r = x.u + 0x7fffu + ((x.u >> 16) & 1u);
    return (unsigned short)(r >> 16);
}

// async global->LDS DMA, 16B per lane (dest = uniform base + lane*16)
__device__ inline void dma16(const unsigned short* g, unsigned short* l) {
    __builtin_amdgcn_global_load_lds(
        (const __attribute__((address_space(1))) void*)g,
        (__attribute__((address_space(3))) void*)l, 16, 0, 0);
}

// ---------------------------------------------------------------------------
// Weight transpose + cast: W (K=1024, N=1024) fp32 -> Wt (N, K) bf16
// ---------------------------------------------------------------------------
__global__ __launch_bounds__(256) void transpose_w(const float* __restrict__ W,
                                                   unsigned short* __restrict__ Wt) {
    __shared__ float tile[32][33];
    int n0 = blockIdx.x * 32, k0 = blockIdx.y * 32;
    int tx = threadIdx.x, ty = threadIdx.y;   // (32, 8)
    #pragma unroll
    for (int i = 0; i < 32; i += 8)
        tile[ty + i][tx] = W[(size_t)(k0 + ty + i) * Dm + n0 + tx];
    __syncthreads();
    #pragma unroll
    for (int i = 0; i < 32; i += 8)
        Wt[(size_t)(n0 + ty + i) * Dm + k0 + tx] = f32_to_bf16(tile[tx][ty + i]);
}

// ---------------------------------------------------------------------------
// Projection GEMM: A (8192 x 1024 fp32) @ Wt^T (+bias) -> bf16 out
// mode 0: out[((b*H+h)*S + s)*64 + d]                    (Q, K layout)
// mode 1: out[(((b*H+h)*32 + s/64)*64 + d)*64 + s%64]    (V tile-blocked)
// ---------------------------------------------------------------------------
__global__ __launch_bounds__(256) void gemm_proj(const float* __restrict__ A,
                                                 const unsigned short* __restrict__ Bt,
                                                 const float* __restrict__ bias,
                                                 unsigned short* __restrict__ Out,
                                                 int mode) {
    const int wave = threadIdx.x >> 6;
    const int lane = threadIdx.x & 63;
    const int quad = lane >> 4;
    const int l16  = lane & 15;
    const int row_base = blockIdx.x * 64 + (wave & 1) * 32;
    const int col_base = blockIdx.y * 128 + (wave >> 1) * 64;

    floatx4 acc[2][4] = {};

    for (int k0 = 0; k0 < Dm; k0 += 32) {
        const int kk = k0 + quad * 8;
        short8 a[2], b[4];
        #pragma unroll
        for (int r = 0; r < 2; r++) {
            const floatx4* ap = (const floatx4*)(A + (size_t)(row_base + r * 16 + l16) * Dm + kk);
            floatx4 f0 = ap[0], f1 = ap[1];
            union { short8 v; unsigned short u[8]; } av;
            #pragma unroll
            for (int j = 0; j < 4; j++) {
                av.u[j]     = f32_to_bf16(f0[j]);
                av.u[4 + j] = f32_to_bf16(f1[j]);
            }
            a[r] = av.v;
        }
        #pragma unroll
        for (int c = 0; c < 4; c++)
            b[c] = *(const short8*)(Bt + (size_t)(col_base + c * 16 + l16) * Dm + kk);
        #pragma unroll
        for (int r = 0; r < 2; r++)
            #pragma unroll
            for (int c = 0; c < 4; c++)
                acc[r][c] = __builtin_amdgcn_mfma_f32_16x16x32_bf16(a[r], b[c], acc[r][c], 0, 0, 0);
    }

    #pragma unroll
    for (int r = 0; r < 2; r++)
        #pragma unroll
        for (int c = 0; c < 4; c++) {
            int n = col_base + c * 16 + l16;
            float bias_n = bias[n];
            int h = n >> 6, d = n & 63;
            #pragma unroll
            for (int i = 0; i < 4; i++) {
                int m = row_base + r * 16 + quad * 4 + i;
                unsigned short ob = f32_to_bf16(acc[r][c][i] + bias_n);
                int bb = m >> 11, s = m & (Ss - 1);
                if (mode == 0)
                    Out[((size_t)(bb * Hh + h) * Ss + s) * 64 + d] = ob;
                else
                    Out[(((size_t)(bb * Hh + h) * 32 + (s >> 6)) * 64 + d) * 64 + (s & 63)] = ob;
            }
        }
}

// ---------------------------------------------------------------------------
// Flash attention, transposed-scores form + LDS double-buffered K/V staging.
// Block = (b, h, 64-query tile); 4 waves, each owns 16 queries, all keys.
// Per 64-key tile: DMA next K/V tiles into LDS (global_load_lds, XOR-swizzled
// source so ds_read_b128 fragments are conflict-free) while computing current.
// S^T = K . Q^T (C-layout: col=l16=query, row=quad*4+i=key) => softmax
// reduction = 15 reg ops + 2 shuffles; m/l state one scalar/lane.
// ---------------------------------------------------------------------------
#define PSTRIDE 72   // ushorts per P row (144 B) -> 2-way (free) b64/b128
#define SCL 0.18033688f      // 0.125 * log2(e)
#define PEN 1.44269504e12f   // 1e12 * log2(e)  (matches reference NEG_BIG)

__global__ __launch_bounds__(256) void attn_kernel(const unsigned short* __restrict__ Qp,
                                                   const unsigned short* __restrict__ Kp,
                                                   const unsigned short* __restrict__ Vt,
                                                   const int* __restrict__ v_mask,
                                                   unsigned short* __restrict__ AO) {
    const int wave = threadIdx.x >> 6;
    const int lane = threadIdx.x & 63;
    const int quad = lane >> 4;
    const int l16  = lane & 15;
    const int qt = (int)gridDim.x - 1 - (int)blockIdx.x;   // heavy tiles first
    const int h  = blockIdx.y;
    const int b  = blockIdx.z;
    const int bh = b * Hh + h;
    const int qbase = qt * 64 + wave * 16;
    const int query = qbase + l16;

    // LDS: K/V double buffers (8KB tiles) + per-wave P transpose scratch
    __shared__ __align__(16) unsigned short Klds[2][4096];
    __shared__ __align__(16) unsigned short Vlds[2][4096];
    __shared__ __align__(16) unsigned short P_lds[4][16 * PSTRIDE];
    unsigned short* Pw = &P_lds[wave][0];

    // per-lane DMA source offsets (XOR-swizzled chunk permutation).
    // global tile = 64 rows x 64 ushorts; chunk G (=16B) lands at LDS chunk G,
    // sourced from row=G/8, colchunk=(G%8)^(row&7).
    int dmaOff[2], dmaDst[2];
    #pragma unroll
    for (int i = 0; i < 2; i++) {
        int G = (wave * 2 + i) * 64 + lane;
        int row = G >> 3, c = G & 7;
        dmaOff[i] = row * 64 + (c ^ (row & 7)) * 8;   // ushort units
        dmaDst[i] = (wave * 2 + i) * 512;             // ushort units (uniform)
    }
    const unsigned short* Kt_base = Kp + (size_t)bh * Ss * 64;      // + kt*4096
    const unsigned short* Vt_base = Vt + (size_t)bh * 32 * 4096;    // + kt*4096

    // Q B-fragments (n = query = l16, k = quad*8+j [+32])
    const unsigned short* qptr = Qp + ((size_t)bh * Ss + qbase + l16) * 64 + quad * 8;
    const short8 qf0 = *(const short8*)(qptr);
    const short8 qf1 = *(const short8*)(qptr + 32);

    // swizzled fragment read offsets within a 64x64 LDS tile
    const int slot0 = (quad ^ (l16 & 7)) * 8;          // ushort units
    const int slot1 = slot0 ^ 32;

    floatx4 o[4] = {};
    float mrun = -3e38f;   // per query (=l16), uniform across quads
    float lrun = 0.f;

    // prologue: stage tile 0
    #pragma unroll
    for (int i = 0; i < 2; i++) {
        dma16(Kt_base + dmaOff[i], &Klds[0][dmaDst[i]]);
        dma16(Vt_base + dmaOff[i], &Vlds[0][dmaDst[i]]);
    }
    __syncthreads();

    int cur = 0;
    for (int kt = 0; kt <= qt; kt++) {
        const int kk = kt * 64;

        // stage tile kt+1 while computing tile kt
        if (kt < qt) {
            const unsigned short* kn = Kt_base + (size_t)(kt + 1) * 4096;
            const unsigned short* vn = Vt_base + (size_t)(kt + 1) * 4096;
            #pragma unroll
            for (int i = 0; i < 2; i++) {
                dma16(kn + dmaOff[i], &Klds[cur ^ 1][dmaDst[i]]);
                dma16(vn + dmaOff[i], &Vlds[cur ^ 1][dmaDst[i]]);
            }
        }

        const unsigned short* Kc = &Klds[cur][0];
        const unsigned short* Vc = &Vlds[cur][0];

        // --- S^T = K . Q^T : A = K rows (m = key), B = Q ---
        floatx4 st[4];
        #pragma unroll
        for (int kf = 0; kf < 4; kf++) {
            const unsigned short* kp = Kc + (kf * 16 + l16) * 64;
            short8 a0 = *(const short8*)(kp + slot0);
            short8 a1 = *(const short8*)(kp + slot1);
            floatx4 t = {};
            t = __builtin_amdgcn_mfma_f32_16x16x32_bf16(a0, qf0, t, 0, 0, 0);
            t = __builtin_amdgcn_mfma_f32_16x16x32_bf16(a1, qf1, t, 0, 0, 0);
            st[kf] = t;
        }

        // --- scale + mask (log2 domain), per-lane max over 16 keys ---
        float sv[4][4];
        float mloc = -3e38f;
        #pragma unroll
        for (int kf = 0; kf < 4; kf++) {
            const int4 vm = *(const int4*)(v_mask + b * Ss + kk + kf * 16 + quad * 4);
            const int vmi[4] = {vm.x, vm.y, vm.z, vm.w};
            #pragma unroll
            for (int i = 0; i < 4; i++) {
                const int key = kk + kf * 16 + quad * 4 + i;
                float pen = (vmi[i] == 0) ? PEN : 0.f;
                if (key > query) pen += PEN;
                sv[kf][i] = fmaf(st[kf][i], SCL, -pen);
                mloc = fmaxf(mloc, sv[kf][i]);
            }
        }
        mloc = fmaxf(mloc, __shfl_xor(mloc, 16, 64));
        mloc = fmaxf(mloc, __shfl_xor(mloc, 32, 64));
        const float mnew = fmaxf(mrun, mloc);
        const float alpha = exp2f(mrun - mnew);
        mrun = mnew;

        // --- exp, per-lane sum, pack P^T -> LDS as P[query][key_local] ---
        float ps = 0.f;
        #pragma unroll
        for (int kf = 0; kf < 4; kf++) {
            union { short4v v; unsigned short u[4]; } pk;
            #pragma unroll
            for (int i = 0; i < 4; i++) {
                const float p = exp2f(sv[kf][i] - mnew);
                ps += p;
                pk.u[i] = f32_to_bf16(p);
            }
            *(short4v*)(Pw + l16 * PSTRIDE + kf * 16 + quad * 4) = pk.v;
        }
        ps += __shfl_xor(ps, 16, 64);
        ps += __shfl_xor(ps, 32, 64);
        lrun = lrun * alpha + ps;

        // --- rescale O by alpha (query -> row axis: 4 bpermute) ---
        float ai[4];
        #pragma unroll
        for (int i = 0; i < 4; i++)
            ai[i] = __shfl(alpha, quad * 4 + i, 64);
        #pragma unroll
        for (int f = 0; f < 4; f++)
            #pragma unroll
            for (int i = 0; i < 4; i++)
                o[f][i] *= ai[i];

        // --- P A-frags from LDS (per-wave private) ---
        const short8 pa0 = *(const short8*)(Pw + l16 * PSTRIDE + quad * 8);
        const short8 pa1 = *(const short8*)(Pw + l16 * PSTRIDE + 32 + quad * 8);

        // --- O += P . V : B = V rows (n = dv), k = key ---
        #pragma unroll
        for (int f = 0; f < 4; f++) {
            const unsigned short* vp = Vc + (f * 16 + l16) * 64;
            short8 v0 = *(const short8*)(vp + slot0);
            short8 v1 = *(const short8*)(vp + slot1);
            o[f] = __builtin_amdgcn_mfma_f32_16x16x32_bf16(pa0, v0, o[f], 0, 0, 0);
            o[f] = __builtin_amdgcn_mfma_f32_16x16x32_bf16(pa1, v1, o[f], 0, 0, 0);
        }

        __syncthreads();   // all waves done with buf[cur]; DMA into cur^1 drained
        cur ^= 1;
    }

    // epilogue: divide by row sums (redistribute l), write (B, S, H*64) bf16
    float ri[4];
    #pragma unroll
    for (int i = 0; i < 4; i++)
        ri[i] = 1.0f / __shfl(lrun, quad * 4 + i, 64);
    #pragma unroll
    for (int f = 0; f < 4; f++) {
        const int d = h * 64 + f * 16 + l16;
        #pragma unroll
        for (int i = 0; i < 4; i++) {
            const float val = o[f][i] * ri[i];
            AO[((size_t)b * Ss + qbase + quad * 4 + i) * (Hh * DVv) + d] = f32_to_bf16(val);
        }
    }
}

// ---------------------------------------------------------------------------
// Output GEMM: AO (8192 x 1024 bf16) @ Wot^T + bo, * q_mask -> fp32 d_out
// ---------------------------------------------------------------------------
__global__ __launch_bounds__(256) void gemm_final(const unsigned short* __restrict__ A,
                                                  const unsigned short* __restrict__ Bt,
                                                  const float* __restrict__ bias,
                                                  const int* __restrict__ q_mask,
                                                  float* __restrict__ Out) {
    const int wave = threadIdx.x >> 6;
    const int lane = threadIdx.x & 63;
    const int quad = lane >> 4;
    const int l16  = lane & 15;
    const int row_base = blockIdx.x * 64 + (wave & 1) * 32;
    const int col_base = blockIdx.y * 128 + (wave >> 1) * 64;

    floatx4 acc[2][4] = {};

    for (int k0 = 0; k0 < Dm; k0 += 32) {
        const int kk = k0 + quad * 8;
        short8 a[2], b[4];
        #pragma unroll
        for (int r = 0; r < 2; r++)
            a[r] = *(const short8*)(A + (size_t)(row_base + r * 16 + l16) * Dm + kk);
        #pragma unroll
        for (int c = 0; c < 4; c++)
            b[c] = *(const short8*)(Bt + (size_t)(col_base + c * 16 + l16) * Dm + kk);
        #pragma unroll
        for (int r = 0; r < 2; r++)
            #pragma unroll
            for (int c = 0; c < 4; c++)
                acc[r][c] = __builtin_amdgcn_mfma_f32_16x16x32_bf16(a[r], b[c], acc[r][c], 0, 0, 0);
    }

    #pragma unroll
    for (int r = 0; r < 2; r++)
        #pragma unroll
        for (int c = 0; c < 4; c++) {
            int n = col_base + c * 16 + l16;
            float bias_n = bias[n];
            #pragma unroll
            for (int i = 0; i < 4; i++) {
                int m = row_base + r * 16 + quad * 4 + i;
                float qm = (float)q_mask[m];
                Out[(size_t)m * Dm + n] = (acc[r][c][i] + bias_n) * qm;
            }
        }
}

// ---------------------------------------------------------------------------
extern "C" void kernel_launch(void* const* d_in, const int* in_sizes, int n_in,
                              void* d_out, int out_size, void* d_ws, size_t ws_size,
                              hipStream_t stream) {
    const float* q      = (const float*)d_in[0];
    const float* k      = (const float*)d_in[1];
    const float* v      = (const float*)d_in[2];
    const int*   q_mask = (const int*)d_in[3];
    const int*   v_mask = (const int*)d_in[4];
    const float* Wq     = (const float*)d_in[5];
    const float* bq     = (const float*)d_in[6];
    const float* Wk     = (const float*)d_in[7];
    const float* bk     = (const float*)d_in[8];
    const float* Wv     = (const float*)d_in[9];
    const float* bv     = (const float*)d_in[10];
    const float* Wo     = (const float*)d_in[11];
    const float* bo     = (const float*)d_in[12];
    float* out = (float*)d_out;

    char* ws = (char*)d_ws;
    const size_t WT_SZ = (size_t)Dm * Dm * 2;                 // 2 MB each
    const size_t QP_SZ = (size_t)Bb * Hh * Ss * 64 * 2;       // 16 MB each
    unsigned short* Wtq = (unsigned short*)(ws);
    unsigned short* Wtk = (unsigned short*)(ws + WT_SZ);
    unsigned short* Wtv = (unsigned short*)(ws + 2 * WT_SZ);
    unsigned short* Wto = (unsigned short*)(ws + 3 * WT_SZ);
    unsigned short* Qp  = (unsigned short*)(ws + 4 * WT_SZ);
    unsigned short* Kp  = (unsigned short*)(ws + 4 * WT_SZ + QP_SZ);
    unsigned short* Vt  = (unsigned short*)(ws + 4 * WT_SZ + 2 * QP_SZ);
    unsigned short* AO  = (unsigned short*)(ws + 4 * WT_SZ + 3 * QP_SZ);

    dim3 tb(32, 8);
    dim3 tg(Dm / 32, Dm / 32);
    hipLaunchKernelGGL(transpose_w, tg, tb, 0, stream, Wq, Wtq);
    hipLaunchKernelGGL(transpose_w, tg, tb, 0, stream, Wk, Wtk);
    hipLaunchKernelGGL(transpose_w, tg, tb, 0, stream, Wv, Wtv);
    hipLaunchKernelGGL(transpose_w, tg, tb, 0, stream, Wo, Wto);

    const int M = Bb * Ss;  // 8192
    dim3 pg(M / 64, Dm / 128);
    hipLaunchKernelGGL(gemm_proj, pg, dim3(256), 0, stream, q, Wtq, bq, Qp, 0);
    hipLaunchKernelGGL(gemm_proj, pg, dim3(256), 0, stream, k, Wtk, bk, Kp, 0);
    hipLaunchKernelGGL(gemm_proj, pg, dim3(256), 0, stream, v, Wtv, bv, Vt, 1);

    dim3 ag(Ss / 64, Hh, Bb);
    hipLaunchKernelGGL(attn_kernel, ag, dim3(256), 0, stream, Qp, Kp, Vt, v_mask, AO);

    dim3 fg(M / 64, Dm / 128);
    hipLaunchKernelGGL(gemm_final, fg, dim3(256), 0, stream, AO, Wto, bo, q_mask, out);
}

// Round 4
// 482.571 us; speedup vs baseline: 2.4619x; 1.6496x over previous
//
#include <hip/hip_runtime.h>
#include <hip/hip_bf16.h>

#define Bb 4
#define Ss 2048
#define Dm 1024
#define Hh 16
#define DKk 64
#define DVv 64

using short8  = __attribute__((ext_vector_type(8))) short;
using short4v = __attribute__((ext_vector_type(4))) short;
using floatx4 = __attribute__((ext_vector_type(4))) float;

__device__ inline unsigned short f32_to_bf16(float f) {
    union { float f; unsigned int u; } x; x.f = f;
    unsigned int r = x.u + 0x7fffu + ((x.u >> 16) & 1u);
    return (unsigned short)(r >> 16);
}

// async global->LDS DMA, 16B per lane (dest = wave-uniform base + lane*16)
__device__ inline void dma16(const unsigned short* g, unsigned short* l) {
    __builtin_amdgcn_global_load_lds(
        (const __attribute__((address_space(1))) void*)g,
        (__attribute__((address_space(3))) void*)l, 16, 0, 0);
}

// ---------------------------------------------------------------------------
// Weight transpose + cast (all 4 weights in one launch, z selects):
// W (K=1024, N=1024) fp32 -> Wt (N, K) bf16
// ---------------------------------------------------------------------------
__global__ __launch_bounds__(256) void transpose_w4(
        const float* __restrict__ W0, const float* __restrict__ W1,
        const float* __restrict__ W2, const float* __restrict__ W3,
        unsigned short* __restrict__ T0, unsigned short* __restrict__ T1,
        unsigned short* __restrict__ T2, unsigned short* __restrict__ T3) {
    const float* W; unsigned short* Wt;
    switch (blockIdx.z) {
        case 0: W = W0; Wt = T0; break;
        case 1: W = W1; Wt = T1; break;
        case 2: W = W2; Wt = T2; break;
        default: W = W3; Wt = T3; break;
    }
    __shared__ float tile[32][33];
    int n0 = blockIdx.x * 32, k0 = blockIdx.y * 32;
    int tx = threadIdx.x, ty = threadIdx.y;   // (32, 8)
    #pragma unroll
    for (int i = 0; i < 32; i += 8)
        tile[ty + i][tx] = W[(size_t)(k0 + ty + i) * Dm + n0 + tx];
    __syncthreads();
    #pragma unroll
    for (int i = 0; i < 32; i += 8)
        Wt[(size_t)(n0 + ty + i) * Dm + k0 + tx] = f32_to_bf16(tile[tx][ty + i]);
}

// ---------------------------------------------------------------------------
// fp32 -> bf16 cast, 8 elements/thread (exact-fit grid, n = 8192*1024)
// ---------------------------------------------------------------------------
__global__ __launch_bounds__(256) void cast_bf16(const float* __restrict__ X,
                                                 unsigned short* __restrict__ Y) {
    const int idx = blockIdx.x * 256 + threadIdx.x;
    const float4* x4 = (const float4*)X;
    float4 f0 = x4[idx * 2], f1 = x4[idx * 2 + 1];
    const float* p0 = (const float*)&f0;
    const float* p1 = (const float*)&f1;
    union { short8 v; unsigned short u[8]; } o;
    #pragma unroll
    for (int j = 0; j < 4; j++) {
        o.u[j]     = f32_to_bf16(p0[j]);
        o.u[4 + j] = f32_to_bf16(p1[j]);
    }
    *(short8*)(Y + (size_t)idx * 8) = o.v;
}

// ---------------------------------------------------------------------------
// m97-structure GEMM: C = A (8192 x 1024 bf16) . Bt^T (+bias)
// 128x128 block tile, BK=32, global_load_lds staging, 2-barrier K-loop.
// LDS chunk swizzle: chunk c' at (row, c') holds global (row, c'^((row>>1)&3))
// -> ds_read_b128 fragments land on 8 distinct bank-groups (2-way = free).
// mode 0: out bf16 [((bb*H+h)*S + s)*64 + d]                  (Q, K layout)
// mode 1: out bf16 [(((bb*H+h)*32 + s/64)*64 + d)*64 + s%64]  (V tile-blocked)
// ---------------------------------------------------------------------------
__global__ __launch_bounds__(256) void gemm_proj(const unsigned short* __restrict__ A,
                                                 const unsigned short* __restrict__ Bt,
                                                 const float* __restrict__ bias,
                                                 unsigned short* __restrict__ Out,
                                                 int mode) {
    const int wave = threadIdx.x >> 6;
    const int lane = threadIdx.x & 63;
    const int quad = lane >> 4;
    const int l16  = lane & 15;
    const int wr = wave & 1, wc = wave >> 1;
    const int m0 = blockIdx.x * 128;
    const int n0 = blockIdx.y * 128;

    __shared__ __align__(16) unsigned short Alds[4096];
    __shared__ __align__(16) unsigned short Blds[4096];

    // DMA mapping: 512 chunks of 16B per tile; 2 issues/wave/tile
    const unsigned short* Asrc[2];
    const unsigned short* Bsrc[2];
    int Ldst[2];
    #pragma unroll
    for (int i = 0; i < 2; i++) {
        int L = (wave * 2 + i) * 64 + lane;
        int row = L >> 2, cpr = L & 3;
        int csrc = cpr ^ ((row >> 1) & 3);
        Ldst[i] = (wave * 2 + i) * 512;
        Asrc[i] = A  + (size_t)(m0 + row) * Dm + csrc * 8;
        Bsrc[i] = Bt + (size_t)(n0 + row) * Dm + csrc * 8;
    }

    // fragment read offsets (swizzled)
    int aoff[4], boff[4];
    #pragma unroll
    for (int r = 0; r < 4; r++) {
        int row = wr * 64 + r * 16 + l16;
        aoff[r] = row * 32 + (quad ^ ((row >> 1) & 3)) * 8;
        row = wc * 64 + r * 16 + l16;
        boff[r] = row * 32 + (quad ^ ((row >> 1) & 3)) * 8;
    }

    floatx4 acc[4][4] = {};

    for (int k0 = 0; k0 < Dm; k0 += 32) {
        __syncthreads();   // all waves done reading LDS from prev iter
        #pragma unroll
        for (int i = 0; i < 2; i++) {
            dma16(Asrc[i] + k0, &Alds[Ldst[i]]);
            dma16(Bsrc[i] + k0, &Blds[Ldst[i]]);
        }
        __syncthreads();   // DMA drained (vmcnt(0) before barrier)

        short8 a[4], b[4];
        #pragma unroll
        for (int r = 0; r < 4; r++) a[r] = *(const short8*)(Alds + aoff[r]);
        #pragma unroll
        for (int c = 0; c < 4; c++) b[c] = *(const short8*)(Blds + boff[c]);
        #pragma unroll
        for (int r = 0; r < 4; r++)
            #pragma unroll
            for (int c = 0; c < 4; c++)
                acc[r][c] = __builtin_amdgcn_mfma_f32_16x16x32_bf16(a[r], b[c], acc[r][c], 0, 0, 0);
    }

    #pragma unroll
    for (int r = 0; r < 4; r++)
        #pragma unroll
        for (int c = 0; c < 4; c++) {
            int n = n0 + wc * 64 + c * 16 + l16;
            float bias_n = bias[n];
            int h = n >> 6, d = n & 63;
            #pragma unroll
            for (int i = 0; i < 4; i++) {
                int m = m0 + wr * 64 + r * 16 + quad * 4 + i;
                unsigned short ob = f32_to_bf16(acc[r][c][i] + bias_n);
                int bb = m >> 11, s = m & (Ss - 1);
                if (mode == 0)
                    Out[((size_t)(bb * Hh + h) * Ss + s) * 64 + d] = ob;
                else
                    Out[(((size_t)(bb * Hh + h) * 32 + (s >> 6)) * 64 + d) * 64 + (s & 63)] = ob;
            }
        }
}

// ---------------------------------------------------------------------------
// m97-structure final GEMM: AO (8192 x 1024 bf16) @ Wot^T + bo, * q_mask
// -> fp32 d_out
// ---------------------------------------------------------------------------
__global__ __launch_bounds__(256) void gemm_final(const unsigned short* __restrict__ A,
                                                  const unsigned short* __restrict__ Bt,
                                                  const float* __restrict__ bias,
                                                  const int* __restrict__ q_mask,
                                                  float* __restrict__ Out) {
    const int wave = threadIdx.x >> 6;
    const int lane = threadIdx.x & 63;
    const int quad = lane >> 4;
    const int l16  = lane & 15;
    const int wr = wave & 1, wc = wave >> 1;
    const int m0 = blockIdx.x * 128;
    const int n0 = blockIdx.y * 128;

    __shared__ __align__(16) unsigned short Alds[4096];
    __shared__ __align__(16) unsigned short Blds[4096];

    const unsigned short* Asrc[2];
    const unsigned short* Bsrc[2];
    int Ldst[2];
    #pragma unroll
    for (int i = 0; i < 2; i++) {
        int L = (wave * 2 + i) * 64 + lane;
        int row = L >> 2, cpr = L & 3;
        int csrc = cpr ^ ((row >> 1) & 3);
        Ldst[i] = (wave * 2 + i) * 512;
        Asrc[i] = A  + (size_t)(m0 + row) * Dm + csrc * 8;
        Bsrc[i] = Bt + (size_t)(n0 + row) * Dm + csrc * 8;
    }

    int aoff[4], boff[4];
    #pragma unroll
    for (int r = 0; r < 4; r++) {
        int row = wr * 64 + r * 16 + l16;
        aoff[r] = row * 32 + (quad ^ ((row >> 1) & 3)) * 8;
        row = wc * 64 + r * 16 + l16;
        boff[r] = row * 32 + (quad ^ ((row >> 1) & 3)) * 8;
    }

    floatx4 acc[4][4] = {};

    for (int k0 = 0; k0 < Dm; k0 += 32) {
        __syncthreads();
        #pragma unroll
        for (int i = 0; i < 2; i++) {
            dma16(Asrc[i] + k0, &Alds[Ldst[i]]);
            dma16(Bsrc[i] + k0, &Blds[Ldst[i]]);
        }
        __syncthreads();

        short8 a[4], b[4];
        #pragma unroll
        for (int r = 0; r < 4; r++) a[r] = *(const short8*)(Alds + aoff[r]);
        #pragma unroll
        for (int c = 0; c < 4; c++) b[c] = *(const short8*)(Blds + boff[c]);
        #pragma unroll
        for (int r = 0; r < 4; r++)
            #pragma unroll
            for (int c = 0; c < 4; c++)
                acc[r][c] = __builtin_amdgcn_mfma_f32_16x16x32_bf16(a[r], b[c], acc[r][c], 0, 0, 0);
    }

    #pragma unroll
    for (int r = 0; r < 4; r++)
        #pragma unroll
        for (int c = 0; c < 4; c++) {
            int n = n0 + wc * 64 + c * 16 + l16;
            float bias_n = bias[n];
            #pragma unroll
            for (int i = 0; i < 4; i++) {
                int m = m0 + wr * 64 + r * 16 + quad * 4 + i;
                float qm = (float)q_mask[m];
                Out[(size_t)m * Dm + n] = (acc[r][c][i] + bias_n) * qm;
            }
        }
}

// ---------------------------------------------------------------------------
// Flash attention (unchanged from round 3): transposed scores + dbuf staging.
// ---------------------------------------------------------------------------
#define PSTRIDE 72   // ushorts per P row (144 B) -> 2-way (free) b64/b128
#define SCL 0.18033688f      // 0.125 * log2(e)
#define PEN 1.44269504e12f   // 1e12 * log2(e)  (matches reference NEG_BIG)

__global__ __launch_bounds__(256) void attn_kernel(const unsigned short* __restrict__ Qp,
                                                   const unsigned short* __restrict__ Kp,
                                                   const unsigned short* __restrict__ Vt,
                                                   const int* __restrict__ v_mask,
                                                   unsigned short* __restrict__ AO) {
    const int wave = threadIdx.x >> 6;
    const int lane = threadIdx.x & 63;
    const int quad = lane >> 4;
    const int l16  = lane & 15;
    const int qt = (int)gridDim.x - 1 - (int)blockIdx.x;   // heavy tiles first
    const int h  = blockIdx.y;
    const int b  = blockIdx.z;
    const int bh = b * Hh + h;
    const int qbase = qt * 64 + wave * 16;
    const int query = qbase + l16;

    __shared__ __align__(16) unsigned short Klds[2][4096];
    __shared__ __align__(16) unsigned short Vlds[2][4096];
    __shared__ __align__(16) unsigned short P_lds[4][16 * PSTRIDE];
    unsigned short* Pw = &P_lds[wave][0];

    int dmaOff[2], dmaDst[2];
    #pragma unroll
    for (int i = 0; i < 2; i++) {
        int G = (wave * 2 + i) * 64 + lane;
        int row = G >> 3, c = G & 7;
        dmaOff[i] = row * 64 + (c ^ (row & 7)) * 8;
        dmaDst[i] = (wave * 2 + i) * 512;
    }
    const unsigned short* Kt_base = Kp + (size_t)bh * Ss * 64;
    const unsigned short* Vt_base = Vt + (size_t)bh * 32 * 4096;

    const unsigned short* qptr = Qp + ((size_t)bh * Ss + qbase + l16) * 64 + quad * 8;
    const short8 qf0 = *(const short8*)(qptr);
    const short8 qf1 = *(const short8*)(qptr + 32);

    const int slot0 = (quad ^ (l16 & 7)) * 8;
    const int slot1 = slot0 ^ 32;

    floatx4 o[4] = {};
    float mrun = -3e38f;
    float lrun = 0.f;

    #pragma unroll
    for (int i = 0; i < 2; i++) {
        dma16(Kt_base + dmaOff[i], &Klds[0][dmaDst[i]]);
        dma16(Vt_base + dmaOff[i], &Vlds[0][dmaDst[i]]);
    }
    __syncthreads();

    int cur = 0;
    for (int kt = 0; kt <= qt; kt++) {
        const int kk = kt * 64;

        if (kt < qt) {
            const unsigned short* kn = Kt_base + (size_t)(kt + 1) * 4096;
            const unsigned short* vn = Vt_base + (size_t)(kt + 1) * 4096;
            #pragma unroll
            for (int i = 0; i < 2; i++) {
                dma16(kn + dmaOff[i], &Klds[cur ^ 1][dmaDst[i]]);
                dma16(vn + dmaOff[i], &Vlds[cur ^ 1][dmaDst[i]]);
            }
        }

        const unsigned short* Kc = &Klds[cur][0];
        const unsigned short* Vc = &Vlds[cur][0];

        floatx4 st[4];
        #pragma unroll
        for (int kf = 0; kf < 4; kf++) {
            const unsigned short* kp = Kc + (kf * 16 + l16) * 64;
            short8 a0 = *(const short8*)(kp + slot0);
            short8 a1 = *(const short8*)(kp + slot1);
            floatx4 t = {};
            t = __builtin_amdgcn_mfma_f32_16x16x32_bf16(a0, qf0, t, 0, 0, 0);
            t = __builtin_amdgcn_mfma_f32_16x16x32_bf16(a1, qf1, t, 0, 0, 0);
            st[kf] = t;
        }

        float sv[4][4];
        float mloc = -3e38f;
        #pragma unroll
        for (int kf = 0; kf < 4; kf++) {
            const int4 vm = *(const int4*)(v_mask + b * Ss + kk + kf * 16 + quad * 4);
            const int vmi[4] = {vm.x, vm.y, vm.z, vm.w};
            #pragma unroll
            for (int i = 0; i < 4; i++) {
                const int key = kk + kf * 16 + quad * 4 + i;
                float pen = (vmi[i] == 0) ? PEN : 0.f;
                if (key > query) pen += PEN;
                sv[kf][i] = fmaf(st[kf][i], SCL, -pen);
                mloc = fmaxf(mloc, sv[kf][i]);
            }
        }
        mloc = fmaxf(mloc, __shfl_xor(mloc, 16, 64));
        mloc = fmaxf(mloc, __shfl_xor(mloc, 32, 64));
        const float mnew = fmaxf(mrun, mloc);
        const float alpha = exp2f(mrun - mnew);
        mrun = mnew;

        float ps = 0.f;
        #pragma unroll
        for (int kf = 0; kf < 4; kf++) {
            union { short4v v; unsigned short u[4]; } pk;
            #pragma unroll
            for (int i = 0; i < 4; i++) {
                const float p = exp2f(sv[kf][i] - mnew);
                ps += p;
                pk.u[i] = f32_to_bf16(p);
            }
            *(short4v*)(Pw + l16 * PSTRIDE + kf * 16 + quad * 4) = pk.v;
        }
        ps += __shfl_xor(ps, 16, 64);
        ps += __shfl_xor(ps, 32, 64);
        lrun = lrun * alpha + ps;

        float ai[4];
        #pragma unroll
        for (int i = 0; i < 4; i++)
            ai[i] = __shfl(alpha, quad * 4 + i, 64);
        #pragma unroll
        for (int f = 0; f < 4; f++)
            #pragma unroll
            for (int i = 0; i < 4; i++)
                o[f][i] *= ai[i];

        const short8 pa0 = *(const short8*)(Pw + l16 * PSTRIDE + quad * 8);
        const short8 pa1 = *(const short8*)(Pw + l16 * PSTRIDE + 32 + quad * 8);

        #pragma unroll
        for (int f = 0; f < 4; f++) {
            const unsigned short* vp = Vc + (f * 16 + l16) * 64;
            short8 v0 = *(const short8*)(vp + slot0);
            short8 v1 = *(const short8*)(vp + slot1);
            o[f] = __builtin_amdgcn_mfma_f32_16x16x32_bf16(pa0, v0, o[f], 0, 0, 0);
            o[f] = __builtin_amdgcn_mfma_f32_16x16x32_bf16(pa1, v1, o[f], 0, 0, 0);
        }

        __syncthreads();
        cur ^= 1;
    }

    float ri[4];
    #pragma unroll
    for (int i = 0; i < 4; i++)
        ri[i] = 1.0f / __shfl(lrun, quad * 4 + i, 64);
    #pragma unroll
    for (int f = 0; f < 4; f++) {
        const int d = h * 64 + f * 16 + l16;
        #pragma unroll
        for (int i = 0; i < 4; i++) {
            const float val = o[f][i] * ri[i];
            AO[((size_t)b * Ss + qbase + quad * 4 + i) * (Hh * DVv) + d] = f32_to_bf16(val);
        }
    }
}

// ---------------------------------------------------------------------------
extern "C" void kernel_launch(void* const* d_in, const int* in_sizes, int n_in,
                              void* d_out, int out_size, void* d_ws, size_t ws_size,
                              hipStream_t stream) {
    const float* q      = (const float*)d_in[0];
    const float* k      = (const float*)d_in[1];
    const float* v      = (const float*)d_in[2];
    const int*   q_mask = (const int*)d_in[3];
    const int*   v_mask = (const int*)d_in[4];
    const float* Wq     = (const float*)d_in[5];
    const float* bq     = (const float*)d_in[6];
    const float* Wk     = (const float*)d_in[7];
    const float* bk     = (const float*)d_in[8];
    const float* Wv     = (const float*)d_in[9];
    const float* bv     = (const float*)d_in[10];
    const float* Wo     = (const float*)d_in[11];
    const float* bo     = (const float*)d_in[12];
    float* out = (float*)d_out;

    char* ws = (char*)d_ws;
    const size_t WT_SZ = (size_t)Dm * Dm * 2;                 // 2 MB each
    const size_t QP_SZ = (size_t)Bb * Hh * Ss * 64 * 2;       // 16 MB each
    unsigned short* Wtq = (unsigned short*)(ws);
    unsigned short* Wtk = (unsigned short*)(ws + WT_SZ);
    unsigned short* Wtv = (unsigned short*)(ws + 2 * WT_SZ);
    unsigned short* Wto = (unsigned short*)(ws + 3 * WT_SZ);
    unsigned short* Qp  = (unsigned short*)(ws + 4 * WT_SZ);
    unsigned short* Kp  = (unsigned short*)(ws + 4 * WT_SZ + QP_SZ);
    unsigned short* Vt  = (unsigned short*)(ws + 4 * WT_SZ + 2 * QP_SZ);
    unsigned short* AO  = (unsigned short*)(ws + 4 * WT_SZ + 3 * QP_SZ);
    // AO doubles as the bf16-cast scratch for q/k/v (dead until attn writes it)

    hipLaunchKernelGGL(transpose_w4, dim3(Dm / 32, Dm / 32, 4), dim3(32, 8), 0, stream,
                       Wq, Wk, Wv, Wo, Wtq, Wtk, Wtv, Wto);

    const int M = Bb * Ss;  // 8192
    const int castBlocks = M * Dm / (256 * 8);  // exact fit
    dim3 gg(M / 128, Dm / 128);

    hipLaunchKernelGGL(cast_bf16, dim3(castBlocks), dim3(256), 0, stream, q, AO);
    hipLaunchKernelGGL(gemm_proj, gg, dim3(256), 0, stream, AO, Wtq, bq, Qp, 0);
    hipLaunchKernelGGL(cast_bf16, dim3(castBlocks), dim3(256), 0, stream, k, AO);
    hipLaunchKernelGGL(gemm_proj, gg, dim3(256), 0, stream, AO, Wtk, bk, Kp, 0);
    hipLaunchKernelGGL(cast_bf16, dim3(castBlocks), dim3(256), 0, stream, v, AO);
    hipLaunchKernelGGL(gemm_proj, gg, dim3(256), 0, stream, AO, Wtv, bv, Vt, 1);

    dim3 ag(Ss / 64, Hh, Bb);
    hipLaunchKernelGGL(attn_kernel, ag, dim3(256), 0, stream, Qp, Kp, Vt, v_mask, AO);

    hipLaunchKernelGGL(gemm_final, gg, dim3(256), 0, stream, AO, Wto, bo, q_mask, out);
}